// Round 10
// baseline (144.051 us; speedup 1.0000x reference)
//
#include <hip/hip_runtime.h>

// SelfAttention: out = softmax((x Wq^T)(x Wk^T)^T / 32) (x Wv^T)
// N=4096, D=1024, f32 in/out; bf16 MFMA compute.
// v10 = r9 (best: 141.7us) + cast pass fused into QKV:
//  - gemm_qkv reg-stages f32 x/W tiles with v_cvt_pk_bf16_f32 -> ds_write_b128
//    (bit-identical LDS layout/swizzle to the gload_lds path), single barrier
//    per K-tile, T14 issue-early/write-late staging. cast_all DELETED.
//  - S and PV GEMMs unchanged (256x128 tile, 4 waves, BK=32, 2-buf LDS,
//    prefetch-1 + vmcnt(6), XOR swizzle, XCD swizzle, setprio, 2 blocks/CU).

typedef __attribute__((ext_vector_type(8))) __bf16 bf16x8;
typedef __attribute__((ext_vector_type(4))) float floatx4;

#define GLB_AS __attribute__((address_space(1)))
#define LDS_AS __attribute__((address_space(3)))

static __device__ __forceinline__ unsigned short f2bf_u16(float f) {
  union { float f; unsigned u; } x; x.f = f;
  unsigned r = x.u;
  r += 0x7fffu + ((r >> 16) & 1u);   // RNE
  return (unsigned short)(r >> 16);
}
static __device__ __forceinline__ float bf2f(unsigned short u) {
  union { unsigned u; float f; } x; x.u = ((unsigned)u) << 16; return x.f;
}
static __device__ __forceinline__ unsigned cvt_pk_bf16(float lo, float hi) {
  unsigned r;
  asm("v_cvt_pk_bf16_f32 %0, %1, %2" : "=v"(r) : "v"(lo), "v"(hi));
  return r;
}

// ---------------- GEMM: C[M,N] = epi(scale * A[M,K] * B[N,K]^T), bf16 inputs ----------------
// EPI: 0 = PV  (bf16 partial store to c[z])
//      2 = S   (bf16 store of exp to c[0]; per-(colblock,wave) row-sum partials to c[1])
struct GemmOuts { void* c[4]; int ldc[4]; };

template <int EPI>
__global__ __launch_bounds__(256, 2) void gemm_bt(const unsigned short* __restrict__ A,
                                                  const unsigned short* __restrict__ B,
                                                  GemmOuts outs, int lda, int ldb,
                                                  int klen, float scale) {
  // LDS: 2 bufs x (A [256][32] + B [128][32]) = 24576 elems = 48 KiB
  __shared__ unsigned short sh[24576];
  const int t = threadIdx.x;
  const int w = t >> 6, lane = t & 63;
  const int wm = w >> 1, wn = w & 1;        // 2x2 wave grid, wave tile 128x64
  const int gx = gridDim.x;
  const int nwg = gx * gridDim.y;
  int bid = blockIdx.y * gx + blockIdx.x;
  bid = (bid & 7) * (nwg >> 3) + (bid >> 3);
  const int row0 = (bid / gx) * 256;
  const int col0 = (bid % gx) * 128;
  const int z = blockIdx.z;
  const int kstart = z * klen;
  const int NT = klen >> 5;                 // K-tiles of 32 (NT >= 2)

  const int srow = t >> 2;                                  // 0..63
  const int scbe = (((t & 3) ^ ((t >> 3) & 3)) << 3);       // swizzled src col (elems)
  const unsigned short* gA0 = A + (size_t)(row0 + srow) * lda + kstart + scbe;
  const unsigned short* gA1 = gA0 + (size_t)64 * lda;
  const unsigned short* gA2 = gA0 + (size_t)128 * lda;
  const unsigned short* gA3 = gA0 + (size_t)192 * lda;
  const unsigned short* gB0 = B + (size_t)(col0 + srow) * ldb + kstart + scbe;
  const unsigned short* gB1 = gB0 + (size_t)64 * ldb;

#define STAGE(tl_) do { \
    const int bb_ = ((tl_) & 1) * 12288; \
    __builtin_amdgcn_global_load_lds((const GLB_AS void*)(gA0 + (tl_) * 32), \
        (LDS_AS void*)&sh[bb_ + t * 8], 16, 0, 0); \
    __builtin_amdgcn_global_load_lds((const GLB_AS void*)(gA1 + (tl_) * 32), \
        (LDS_AS void*)&sh[bb_ + 2048 + t * 8], 16, 0, 0); \
    __builtin_amdgcn_global_load_lds((const GLB_AS void*)(gA2 + (tl_) * 32), \
        (LDS_AS void*)&sh[bb_ + 4096 + t * 8], 16, 0, 0); \
    __builtin_amdgcn_global_load_lds((const GLB_AS void*)(gA3 + (tl_) * 32), \
        (LDS_AS void*)&sh[bb_ + 6144 + t * 8], 16, 0, 0); \
    __builtin_amdgcn_global_load_lds((const GLB_AS void*)(gB0 + (tl_) * 32), \
        (LDS_AS void*)&sh[bb_ + 8192 + t * 8], 16, 0, 0); \
    __builtin_amdgcn_global_load_lds((const GLB_AS void*)(gB1 + (tl_) * 32), \
        (LDS_AS void*)&sh[bb_ + 10240 + t * 8], 16, 0, 0); \
  } while (0)

  const int fr = lane & 15;
  const int sg = (((lane >> 4) ^ ((lane >> 1) & 3)) << 3);
  int aofs[8], bofs[4];
#pragma unroll
  for (int mf = 0; mf < 8; ++mf) aofs[mf] = ((wm * 128 + mf * 16 + fr) << 5) + sg;
#pragma unroll
  for (int nf = 0; nf < 4; ++nf) bofs[nf] = 8192 + ((wn * 64 + nf * 16 + fr) << 5) + sg;

  floatx4 acc[8][4] = {};

  STAGE(0);

  for (int tile = 0; tile < NT; ++tile) {
    if (tile + 1 < NT) {
      STAGE(tile + 1);
      asm volatile("s_waitcnt vmcnt(6)" ::: "memory");   // tile's own 6 loads landed
    } else {
      asm volatile("s_waitcnt vmcnt(0)" ::: "memory");
    }
    __builtin_amdgcn_s_barrier();   // buf[tile&1] ready for all waves

    const int bo = (tile & 1) * 12288;
    bf16x8 af[8], bf[4];
#pragma unroll
    for (int mf = 0; mf < 8; ++mf) af[mf] = *(const bf16x8*)&sh[bo + aofs[mf]];
#pragma unroll
    for (int nf = 0; nf < 4; ++nf) bf[nf] = *(const bf16x8*)&sh[bo + bofs[nf]];
    __builtin_amdgcn_s_setprio(1);
#pragma unroll
    for (int mf = 0; mf < 8; ++mf)
#pragma unroll
      for (int nf = 0; nf < 4; ++nf)
        acc[mf][nf] = __builtin_amdgcn_mfma_f32_16x16x32_bf16(af[mf], bf[nf], acc[mf][nf], 0, 0, 0);
    __builtin_amdgcn_s_setprio(0);

    __builtin_amdgcn_s_barrier();   // all waves done reading buf[tile&1]
  }
#undef STAGE

  // epilogue: C col = lane&15, row = (lane>>4)*4 + r  [m89-verified]
  const int er = (lane >> 4) * 4;
  const int ec = lane & 15;

  if (EPI == 0) {
    // PV: bf16 partial store
    unsigned short* Cb = (unsigned short*)outs.c[z];
    const int ldc = outs.ldc[z];
#pragma unroll
    for (int mf = 0; mf < 8; ++mf)
#pragma unroll
      for (int nf = 0; nf < 4; ++nf)
#pragma unroll
        for (int r = 0; r < 4; ++r)
          Cb[(size_t)(row0 + wm * 128 + mf * 16 + er + r) * ldc +
             (col0 + wn * 64 + nf * 16 + ec)] = f2bf_u16(acc[mf][nf][r] * scale);
  } else {
    // S: P = bf16(exp(scale*acc)); row-sum partials -> rsp[(col0>>7)*2+wn][m]
    unsigned short* Pb = (unsigned short*)outs.c[0];
    float* rsp = (float*)outs.c[1];
    const int ldc = outs.ldc[0];
    const int rj = ((col0 >> 7) * 2 + wn) * 4096;
#pragma unroll
    for (int mf = 0; mf < 8; ++mf) {
#pragma unroll
      for (int r = 0; r < 4; ++r) {
        const int m = row0 + wm * 128 + mf * 16 + er + r;
        float rsum = 0.f;
#pragma unroll
        for (int nf = 0; nf < 4; ++nf) {
          const float e = __expf(acc[mf][nf][r] * scale);
          Pb[(size_t)m * ldc + (col0 + wn * 64 + nf * 16 + ec)] = f2bf_u16(e);
          rsum += e;
        }
        rsum += __shfl_xor(rsum, 1);
        rsum += __shfl_xor(rsum, 2);
        rsum += __shfl_xor(rsum, 4);
        rsum += __shfl_xor(rsum, 8);
        if (ec == 0) rsp[rj + m] = rsum;   // plain store, unique address
      }
    }
  }
}

// ---------------- QKV GEMM with fused f32->bf16 cast staging ----------------
// A = x f32 [4096][1024]; B = W{q,k,v} f32 [1024][1024] selected by col0.
// q,k -> qkb [4096][2048]; v -> vT [1024][4096] (transposed store).
__global__ __launch_bounds__(256, 2) void gemm_qkv(const float* __restrict__ X,
                                                   const float* __restrict__ Wq,
                                                   const float* __restrict__ Wk,
                                                   const float* __restrict__ Wv,
                                                   unsigned short* __restrict__ qkb,
                                                   unsigned short* __restrict__ vT) {
  __shared__ unsigned short sh[24576];
  const int t = threadIdx.x;
  const int w = t >> 6, lane = t & 63;
  const int wm = w >> 1, wn = w & 1;
  const int gx = gridDim.x;                 // 24
  const int nwg = gx * gridDim.y;           // 384 (%8==0)
  int bid = blockIdx.y * gx + blockIdx.x;
  bid = (bid & 7) * (nwg >> 3) + (bid >> 3);
  const int row0 = (bid / gx) * 256;
  const int col0 = (bid % gx) * 128;
  const float* Wsel = col0 < 1024 ? Wq : (col0 < 2048 ? Wk : Wv);
  const int brow = col0 & 1023;
  const int NT = 32;                        // K=1024 / BK=32

  // identical swizzle mapping to gload_lds path: thread t covers granule (t&3),
  // row (t>>2) of each 64-row region; source col granule XOR'd with (row>>1)&3.
  const int srow = t >> 2;
  const int scbe = (((t & 3) ^ ((t >> 3) & 3)) << 3);
  const float* gA = X + (size_t)(row0 + srow) * 1024 + scbe;
  const float* gB = Wsel + (size_t)(brow + srow) * 1024 + scbe;

  float4 ra[12];
#define LOADF(kt_) do { \
    _Pragma("unroll") for (int r_ = 0; r_ < 4; ++r_) { \
      const float* p_ = gA + (size_t)(r_ * 64) * 1024 + (kt_); \
      ra[2 * r_]     = *(const float4*)p_; \
      ra[2 * r_ + 1] = *(const float4*)(p_ + 4); } \
    _Pragma("unroll") for (int r_ = 0; r_ < 2; ++r_) { \
      const float* p_ = gB + (size_t)(r_ * 64) * 1024 + (kt_); \
      ra[8 + 2 * r_] = *(const float4*)p_; \
      ra[9 + 2 * r_] = *(const float4*)(p_ + 4); } \
  } while (0)
  // pack 8 f32 -> 8 bf16 (RNE via v_cvt_pk_bf16_f32) and write 16B to LDS
#define WRITELDS(bb_) do { \
    _Pragma("unroll") for (int r_ = 0; r_ < 6; ++r_) { \
      uint4 pk_; \
      pk_.x = cvt_pk_bf16(ra[2 * r_].x,     ra[2 * r_].y); \
      pk_.y = cvt_pk_bf16(ra[2 * r_].z,     ra[2 * r_].w); \
      pk_.z = cvt_pk_bf16(ra[2 * r_ + 1].x, ra[2 * r_ + 1].y); \
      pk_.w = cvt_pk_bf16(ra[2 * r_ + 1].z, ra[2 * r_ + 1].w); \
      *(uint4*)&sh[(bb_) + r_ * 2048 + t * 8] = pk_; } \
  } while (0)

  const int fr = lane & 15;
  const int sg = (((lane >> 4) ^ ((lane >> 1) & 3)) << 3);
  int aofs[8], bofs[4];
#pragma unroll
  for (int mf = 0; mf < 8; ++mf) aofs[mf] = ((wm * 128 + mf * 16 + fr) << 5) + sg;
#pragma unroll
  for (int nf = 0; nf < 4; ++nf) bofs[nf] = 8192 + ((wn * 64 + nf * 16 + fr) << 5) + sg;

  floatx4 acc[8][4] = {};

  // prologue: stage tile 0, issue tile 1 loads
  LOADF(0);
  asm volatile("s_waitcnt vmcnt(0)" ::: "memory");
  WRITELDS(0);
  LOADF(32);
  asm volatile("s_waitcnt lgkmcnt(0)" ::: "memory");
  __builtin_amdgcn_s_barrier();

  for (int tile = 0; tile < NT; ++tile) {
    const int bo = (tile & 1) * 12288;
    bf16x8 af[8], bf[4];
#pragma unroll
    for (int mf = 0; mf < 8; ++mf) af[mf] = *(const bf16x8*)&sh[bo + aofs[mf]];
#pragma unroll
    for (int nf = 0; nf < 4; ++nf) bf[nf] = *(const bf16x8*)&sh[bo + bofs[nf]];
    __builtin_amdgcn_s_setprio(1);
#pragma unroll
    for (int mf = 0; mf < 8; ++mf)
#pragma unroll
      for (int nf = 0; nf < 4; ++nf)
        acc[mf][nf] = __builtin_amdgcn_mfma_f32_16x16x32_bf16(af[mf], bf[nf], acc[mf][nf], 0, 0, 0);
    __builtin_amdgcn_s_setprio(0);

    if (tile + 1 < NT) {
      // buf[(tile+1)&1] was read at tile-1 and freed by the end-of-(tile-1)
      // barrier -> safe to overwrite now (before this tile's end barrier).
      asm volatile("s_waitcnt vmcnt(0)" ::: "memory");    // tile+1 regs landed
      WRITELDS(((tile + 1) & 1) * 12288);
      if (tile + 2 < NT) LOADF((tile + 2) * 32);          // issue-early (T14)
    }
    asm volatile("s_waitcnt lgkmcnt(0)" ::: "memory");    // own ds_writes done
    __builtin_amdgcn_s_barrier();                         // end of tile
  }
#undef LOADF
#undef WRITELDS

  // epilogue: C col = lane&15, row = (lane>>4)*4 + r  [m89-verified]
  const int er = (lane >> 4) * 4;
  const int ec = lane & 15;
  if (col0 < 2048) {
#pragma unroll
    for (int mf = 0; mf < 8; ++mf)
#pragma unroll
      for (int nf = 0; nf < 4; ++nf)
#pragma unroll
        for (int r = 0; r < 4; ++r)
          qkb[(size_t)(row0 + wm * 128 + mf * 16 + er + r) * 2048 +
              (col0 + wn * 64 + nf * 16 + ec)] = f2bf_u16(acc[mf][nf][r]);
  } else {
#pragma unroll
    for (int mf = 0; mf < 8; ++mf)
#pragma unroll
      for (int nf = 0; nf < 4; ++nf) {
        const int n = (col0 - 2048) + wn * 64 + nf * 16 + ec;
        const int mb = row0 + wm * 128 + mf * 16 + er;
        ushort4 o = make_ushort4(f2bf_u16(acc[mf][nf][0]), f2bf_u16(acc[mf][nf][1]),
                                 f2bf_u16(acc[mf][nf][2]), f2bf_u16(acc[mf][nf][3]));
        *reinterpret_cast<ushort4*>(&vT[(size_t)n * 4096 + mb]) = o;
      }
  }
}

// ---------------- reduce: out[row] = (p0+p1)[row] / sum_j rsp[j][row] ----------------
__global__ __launch_bounds__(256) void reduce_pv(float* __restrict__ out,
                                                 const unsigned short* __restrict__ p0,
                                                 const unsigned short* __restrict__ p1,
                                                 const float* __restrict__ rsp) {
  const int row = blockIdx.x;
  const int lane = threadIdx.x & 63;
  float s = rsp[lane * 4096 + row];
#pragma unroll
  for (int off = 32; off >= 1; off >>= 1) s += __shfl_xor(s, off);
  const float inv = 1.0f / s;
  const int idx = row * 256 + threadIdx.x;   // ushort4 / float4 index
  ushort4 a = ((const ushort4*)p0)[idx];
  ushort4 b = ((const ushort4*)p1)[idx];
  float4 o;
  o.x = (bf2f(a.x) + bf2f(b.x)) * inv;
  o.y = (bf2f(a.y) + bf2f(b.y)) * inv;
  o.z = (bf2f(a.z) + bf2f(b.z)) * inv;
  o.w = (bf2f(a.w) + bf2f(b.w)) * inv;
  ((float4*)out)[idx] = o;
}

extern "C" void kernel_launch(void* const* d_in, const int* in_sizes, int n_in,
                              void* d_out, int out_size, void* d_ws, size_t ws_size,
                              hipStream_t stream) {
  const float* x  = (const float*)d_in[0];
  const float* Wq = (const float*)d_in[1];
  const float* Wk = (const float*)d_in[2];
  const float* Wv = (const float*)d_in[3];
  float* out = (float*)d_out;

  const int N = 4096, D = 1024;

  // workspace (~80 MB):
  // [0,32)   P bf16 [4096][4096] = exp(scores)
  // [32,48)  qkb bf16 [4096][2048]  (q | k)
  // [48,56)  vT bf16 [1024][4096]
  // [56,64)  p0 bf16 [4096][1024]
  // [70,71)  rsp f32 [64][4096] row-sum partials
  // [72,80)  p1 bf16 [4096][1024]
  char* ws = (char*)d_ws;
  unsigned short* P   = (unsigned short*)ws;
  unsigned short* qkb = (unsigned short*)(ws + (32u << 20));
  unsigned short* vT  = (unsigned short*)(ws + (48u << 20));
  unsigned short* p0  = (unsigned short*)(ws + (56u << 20));
  float*          rsp = (float*)(ws + (70u << 20));
  unsigned short* p1  = (unsigned short*)(ws + (72u << 20));

  // qkv = x @ [Wq;Wk;Wv]^T with fused f32->bf16 cast (no cast pass)
  gemm_qkv<<<dim3(3 * D / 128, N / 256, 1), 256, 0, stream>>>(x, Wq, Wk, Wv, qkb, vT);

  // P = exp((q @ k^T)/32); rsp = row-sum partials
  GemmOuts os; os.c[0] = P; os.c[1] = rsp; os.c[2] = os.c[3] = P;
  os.ldc[0] = N; os.ldc[1] = 0; os.ldc[2] = os.ldc[3] = N;
  gemm_bt<2><<<dim3(N / 128, N / 256, 1), 256, 0, stream>>>(qkb, qkb + D, os, 2 * D, 2 * D, D, 0.03125f);

  // partials = P @ v, split-K x2 (bf16): z0 -> p0, z1 -> p1
  GemmOuts op;
  op.c[0] = p0; op.ldc[0] = D;
  op.c[1] = p1; op.ldc[1] = D;
  op.c[2] = p0; op.ldc[2] = D;
  op.c[3] = p1; op.ldc[3] = D;
  gemm_bt<0><<<dim3(D / 128, N / 256, 2), 256, 0, stream>>>(P, vT, op, N, N, N / 2, 1.0f);

  // out = (p0+p1) / rowsum
  reduce_pv<<<N, 256, 0, stream>>>(out, p0, p1, rsp);
}